// Round 8
// baseline (202.599 us; speedup 1.0000x reference)
//
#include <hip/hip_runtime.h>
#include <hip/hip_bf16.h>

#define NB   16384
#define NE   64
#define DIN  128
#define DOUT 128
#define CPAD 32   // atomic counters on own 128B cache line

// ws layout in 4-byte words
#define WS_COUNTS   0         // 64*CPAD
#define WS_CURSOR   2048      // 64*CPAD
#define WS_BASE     4096      // 64
#define WS_NWORK    4160      // 1
#define WS_WORK     4224      // <= 832
#define WS_PICKED   8192      // 3*NB
#define WS_PW       57344     // 3*NB
#define WS_PAIRROW  106496    // 3*NB
#define WS_PAIRW    155648    // 3*NB
#define WS_PAIRP    204800    // 3*NB
#define WS_SLOT     253952    // 3*NB*128 floats
#define MAX_WORK    832

typedef __attribute__((ext_vector_type(8))) short short8v;
typedef __attribute__((ext_vector_type(4))) float f32x4;

static __device__ __forceinline__ short f2bf(float f) {
  unsigned u = __float_as_uint(f);
  unsigned r = (u + 0x7fffu + ((u >> 16) & 1u)) >> 16;   // RNE
  return (short)r;
}
static __device__ __forceinline__ float bf2f(short s) {
  return __uint_as_float(((unsigned)(unsigned short)s) << 16);
}

__global__ __launch_bounds__(64) void k0_init(int* __restrict__ wsI) {
  if (threadIdx.x < NE) wsI[WS_COUNTS + threadIdx.x * CPAD] = 0;
}

__global__ __launch_bounds__(256) void k1_route(
    const float* __restrict__ x, const float* __restrict__ dsc,
    const float* __restrict__ cent, float* __restrict__ out,
    int* __restrict__ wsI, float* __restrict__ wsF, int zero_out) {
  __shared__ float cl[NE][132];
  __shared__ float xl[16][132];
  __shared__ float dl[4][64];
  const int tid = threadIdx.x;
  const int row0 = blockIdx.x * 16;

  const float4* c4 = (const float4*)cent;
  #pragma unroll
  for (int k = 0; k < 8; ++k) {
    int idx = tid + k * 256;
    int e = idx >> 5, dc = idx & 31;
    *(float4*)&cl[e][dc * 4] = c4[idx];
  }
  const float4* x4 = (const float4*)x + row0 * 32;
  #pragma unroll
  for (int k = 0; k < 2; ++k) {
    int idx = tid + k * 256;
    int r = idx >> 5, dc = idx & 31;
    *(float4*)&xl[r][dc * 4] = x4[idx];
  }
  if (zero_out) {
    float4* o4 = (float4*)out + row0 * 32;
    float4 z; z.x = z.y = z.z = z.w = 0.f;
    #pragma unroll
    for (int k = 0; k < 2; ++k) o4[tid + k * 256] = z;
  }
  __syncthreads();

  const int lane = tid & 63, wv = tid >> 6;
  const float ds = dsc[0];

  for (int rr = wv; rr < 16; rr += 4) {
    // distance_sq, numpy pairwise order (8 interleaved accs), contract off
    float4 r0 = {0.f, 0.f, 0.f, 0.f}, r1 = {0.f, 0.f, 0.f, 0.f};
    {
      #pragma clang fp contract(off)
      for (int i = 0; i < 16; ++i) {
        float4 xa = *(const float4*)&xl[rr][i * 8];
        float4 xb = *(const float4*)&xl[rr][i * 8 + 4];
        float4 ca = *(const float4*)&cl[lane][i * 8];
        float4 cb = *(const float4*)&cl[lane][i * 8 + 4];
        float t0 = ds * (xa.x - ca.x), t1 = ds * (xa.y - ca.y);
        float t2 = ds * (xa.z - ca.z), t3 = ds * (xa.w - ca.w);
        float u0 = ds * (xb.x - cb.x), u1 = ds * (xb.y - cb.y);
        float u2 = ds * (xb.z - cb.z), u3 = ds * (xb.w - cb.w);
        r0.x += t0 * t0; r0.y += t1 * t1; r0.z += t2 * t2; r0.w += t3 * t3;
        r1.x += u0 * u0; r1.y += u1 * u1; r1.z += u2 * u2; r1.w += u3 * u3;
      }
    }
    float s = ((r0.x + r0.y) + (r0.z + r0.w)) + ((r1.x + r1.y) + (r1.z + r1.w));
    float dist = s / 128.0f;

    // rank-based top-3; (dist, index) lex order == jax tie rule
    dl[wv][lane] = dist;
    int rank = 0;
    #pragma unroll
    for (int j = 0; j < 64; j += 8) {
      float4 da = *(const float4*)&dl[wv][j];
      float4 db = *(const float4*)&dl[wv][j + 4];
      rank += (da.x < dist || (da.x == dist && (j + 0) < lane)) ? 1 : 0;
      rank += (da.y < dist || (da.y == dist && (j + 1) < lane)) ? 1 : 0;
      rank += (da.z < dist || (da.z == dist && (j + 2) < lane)) ? 1 : 0;
      rank += (da.w < dist || (da.w == dist && (j + 3) < lane)) ? 1 : 0;
      rank += (db.x < dist || (db.x == dist && (j + 4) < lane)) ? 1 : 0;
      rank += (db.y < dist || (db.y == dist && (j + 5) < lane)) ? 1 : 0;
      rank += (db.z < dist || (db.z == dist && (j + 6) < lane)) ? 1 : 0;
      rank += (db.w < dist || (db.w == dist && (j + 7) < lane)) ? 1 : 0;
    }
    unsigned long long m0 = __ballot(rank == 0);
    unsigned long long m1 = __ballot(rank == 1);
    unsigned long long m2 = __ballot(rank == 2);
    int i0 = __ffsll(m0) - 1;
    int i1 = __ffsll(m1) - 1;
    int i2 = __ffsll(m2) - 1;

    float d0 = dl[wv][0], d1 = dl[wv][1], d2 = dl[wv][2];
    float w0 = 1.f / (1.f + d0), w1 = 1.f / (1.f + d1), w2 = 1.f / (1.f + d2);
    float sw = (w0 + w1) + w2;
    w0 /= sw; w1 /= sw; w2 /= sw;

    int row = row0 + rr;
    if (lane < 3) {
      float w = (lane == 0) ? w0 : ((lane == 1) ? w1 : w2);
      int p = (lane == 0) ? i0 : ((lane == 1) ? i1 : i2);
      wsI[WS_PICKED + row * 3 + lane] = p;
      wsF[WS_PW + row * 3 + lane] = w;
      // counting moved to k1b (LDS histogram)
    }
  }
}

// block-LDS histogram -> few padded global atomics
__global__ __launch_bounds__(256) void k1b_count(int* __restrict__ wsI) {
  __shared__ int h[NE];
  const int tid = threadIdx.x;
  if (tid < NE) h[tid] = 0;
  __syncthreads();
  for (int i = blockIdx.x * 256 + tid; i < 3 * NB; i += 64 * 256)
    atomicAdd(&h[wsI[WS_PICKED + i]], 1);
  __syncthreads();
  if (tid < NE && h[tid]) atomicAdd(&wsI[WS_COUNTS + tid * CPAD], h[tid]);
}

__global__ __launch_bounds__(64) void k2_scan(int* __restrict__ wsI) {
  const int lane = threadIdx.x;
  int cnt = wsI[WS_COUNTS + lane * CPAD];
  int xs = cnt;
  #pragma unroll
  for (int off = 1; off < 64; off <<= 1) {
    int y = __shfl_up(xs, off, 64);
    if (lane >= off) xs += y;
  }
  int excl = xs - cnt;
  wsI[WS_BASE + lane] = excl;
  wsI[WS_CURSOR + lane * CPAD] = excl;
  int nt = (cnt + 63) >> 6;
  int ts = nt;
  #pragma unroll
  for (int off = 1; off < 64; off <<= 1) {
    int y = __shfl_up(ts, off, 64);
    if (lane >= off) ts += y;
  }
  int texcl = ts - nt;
  for (int t = 0; t < nt; ++t) wsI[WS_WORK + texcl + t] = (lane << 16) | t;
  if (lane == 63) wsI[WS_NWORK] = ts;
}

__global__ __launch_bounds__(256) void k3_scatter(int* __restrict__ wsI,
                                                  float* __restrict__ wsF) {
  int p = blockIdx.x * 256 + threadIdx.x;
  if (p < 3 * NB) {
    int e = wsI[WS_PICKED + p];
    float w = wsF[WS_PW + p];
    int pos = atomicAdd(&wsI[WS_CURSOR + e * CPAD], 1);
    wsI[WS_PAIRROW + pos] = p / 3;
    wsI[WS_PAIRP + pos]   = p;
    wsF[WS_PAIRW + pos]   = w;
  }
}

// MFMA k4: per (expert, 64-row tile) block, 4 waves, wave w = rows 16w..16w+15.
// Split precision: y = xh*wh + xh*wl + xl*wh (bf16 hi + bf16 residual, f32 acc).
// W staged transposed hi/lo in LDS in two K-halves (stays under 64KB static LDS).
template <int SLOT>
__global__ __launch_bounds__(256) void k4_gemm(
    const float* __restrict__ x, const float* __restrict__ W,
    const float* __restrict__ bias, const int* __restrict__ wsI,
    const float* __restrict__ wsF, float* __restrict__ dst) {
  __shared__ short whT[DOUT][72];   // [o][d-half], stride 144B (16B-aligned)
  __shared__ short wlT[DOUT][72];
  __shared__ float biasl[DOUT];
  __shared__ int   rowsl[64];
  __shared__ int   pl[64];
  __shared__ float wgt[64];

  const int nwork = wsI[WS_NWORK];
  const int bid = blockIdx.x;
  if (bid >= nwork) return;
  const int wk = wsI[WS_WORK + bid];
  const int e = wk >> 16, t = wk & 0xffff;
  const int cnt = wsI[WS_COUNTS + e * CPAD];
  const int srcb = wsI[WS_BASE + e] + t * 64;
  const int m = min(64, cnt - t * 64);
  const int tid = threadIdx.x;
  const int lane = tid & 63, wv = tid >> 6;
  const int l15 = lane & 15, kg = lane >> 4;

  if (tid < 64) {
    int src = srcb + ((tid < m) ? tid : 0);
    rowsl[tid] = wsI[WS_PAIRROW + src];
    pl[tid]    = wsI[WS_PAIRP + src];
    wgt[tid]   = (tid < m) ? wsF[WS_PAIRW + srcb + tid] : 0.f;
  }
  if (tid < DOUT) biasl[tid] = bias[e * DOUT + tid];
  __syncthreads();

  // A fragments: lane (l15,kg) of wave wv covers row rowsl[16*wv+l15],
  // k = 32s + 8kg + i. Load fp32 direct from global, split to bf16 hi/lo.
  const float* xr = x + (long)rowsl[16 * wv + l15] * DIN + 8 * kg;
  short8v ah[4], al[4];
  #pragma unroll
  for (int s = 0; s < 4; ++s) {
    float4 fa = *(const float4*)(xr + 32 * s);
    float4 fb = *(const float4*)(xr + 32 * s + 4);
    float f[8] = {fa.x, fa.y, fa.z, fa.w, fb.x, fb.y, fb.z, fb.w};
    #pragma unroll
    for (int i = 0; i < 8; ++i) {
      short h = f2bf(f[i]);
      ah[s][i] = h;
      al[s][i] = f2bf(f[i] - bf2f(h));
    }
  }

  f32x4 acc[8];
  #pragma unroll
  for (int n = 0; n < 8; ++n) acc[n] = (f32x4){0.f, 0.f, 0.f, 0.f};

  const float* We = W + (long)e * DIN * DOUT;
  // two K-halves: stage W[64 d][128 o] hi/lo transposed, then MFMA s=2*kh+sh
  for (int kh = 0; kh < 2; ++kh) {
    __syncthreads();   // protect LDS reuse from previous half
    {
      // thread t: d = 64*kh + (t&63), o = 32*(t>>6) + 4i
      int d = 64 * kh + (tid & 63);
      int ob = 32 * (tid >> 6);
      const float4* Wg = (const float4*)(We + (long)d * DOUT + ob);
      #pragma unroll
      for (int i = 0; i < 8; ++i) {
        float4 v = Wg[i];
        int o = ob + 4 * i;
        float f[4] = {v.x, v.y, v.z, v.w};
        #pragma unroll
        for (int j = 0; j < 4; ++j) {
          short h = f2bf(f[j]);
          whT[o + j][d - 64 * kh] = h;
          wlT[o + j][d - 64 * kh] = f2bf(f[j] - bf2f(h));
        }
      }
    }
    __syncthreads();

    #pragma unroll
    for (int n = 0; n < 8; ++n) {
      #pragma unroll
      for (int sh = 0; sh < 2; ++sh) {
        int s = 2 * kh + sh;
        // FIX (round 6 bug): B d-offset per subtile is 32, matching A's k
        // coverage [64*kh + 32*sh, +32). Was 16*sh -> A/B k-mismatch for sh=1.
        short8v bh = *(const short8v*)&whT[16 * n + l15][32 * sh + 8 * kg];
        short8v bl = *(const short8v*)&wlT[16 * n + l15][32 * sh + 8 * kg];
        acc[n] = __builtin_amdgcn_mfma_f32_16x16x32_bf16(ah[s], bh, acc[n], 0, 0, 0);
        acc[n] = __builtin_amdgcn_mfma_f32_16x16x32_bf16(ah[s], bl, acc[n], 0, 0, 0);
        acc[n] = __builtin_amdgcn_mfma_f32_16x16x32_bf16(al[s], bh, acc[n], 0, 0, 0);
      }
    }
  }

  // C/D: col = l15 (within n-tile), local row = 16*wv + 4*kg + j
  #pragma unroll
  for (int j = 0; j < 4; ++j) {
    int r = 16 * wv + 4 * kg + j;
    if (r < m) {
      float w = wgt[r];
      #pragma unroll
      for (int n = 0; n < 8; ++n) {
        int o = 16 * n + l15;
        float v = w * (acc[n][j] + biasl[o]);
        if (SLOT) {
          dst[(long)pl[r] * DOUT + o] = v;
        } else {
          atomicAdd(&dst[(long)rowsl[r] * DOUT + o], v);
        }
      }
    }
  }
}

__global__ __launch_bounds__(256) void k5_gather(const float* __restrict__ slot,
                                                 float* __restrict__ out) {
  int gid = blockIdx.x * 256 + threadIdx.x;
  int row = gid >> 5, c4 = gid & 31;
  const float4* s = (const float4*)(slot + (long)row * 3 * DOUT) + c4;
  float4 a = s[0], b = s[32], c = s[64];
  float4 o;
  o.x = (a.x + b.x) + c.x;
  o.y = (a.y + b.y) + c.y;
  o.z = (a.z + b.z) + c.z;
  o.w = (a.w + b.w) + c.w;
  ((float4*)out)[gid] = o;
}

extern "C" void kernel_launch(void* const* d_in, const int* in_sizes, int n_in,
                              void* d_out, int out_size, void* d_ws, size_t ws_size,
                              hipStream_t stream) {
  const float* x    = (const float*)d_in[0];
  const float* dsc  = (const float*)d_in[1];
  const float* cent = (const float*)d_in[2];
  const float* W    = (const float*)d_in[3];
  const float* bias = (const float*)d_in[4];
  float* out = (float*)d_out;
  int* wsI = (int*)d_ws;
  float* wsF = (float*)d_ws;

  const size_t need = ((size_t)WS_SLOT + (size_t)3 * NB * DOUT) * 4;
  const int useSlot = (ws_size >= need) ? 1 : 0;

  hipLaunchKernelGGL(k0_init,    dim3(1),            dim3(64),  0, stream, wsI);
  hipLaunchKernelGGL(k1_route,   dim3(NB / 16),      dim3(256), 0, stream,
                     x, dsc, cent, out, wsI, wsF, useSlot ? 0 : 1);
  hipLaunchKernelGGL(k1b_count,  dim3(64),           dim3(256), 0, stream, wsI);
  hipLaunchKernelGGL(k2_scan,    dim3(1),            dim3(64),  0, stream, wsI);
  hipLaunchKernelGGL(k3_scatter, dim3(3 * NB / 256), dim3(256), 0, stream, wsI, wsF);
  if (useSlot) {
    float* slot = (float*)d_ws + WS_SLOT;
    hipLaunchKernelGGL(k4_gemm<1>, dim3(MAX_WORK),   dim3(256), 0, stream,
                       x, W, bias, wsI, wsF, slot);
    hipLaunchKernelGGL(k5_gather,  dim3(NB * 32 / 256), dim3(256), 0, stream, slot, out);
  } else {
    hipLaunchKernelGGL(k4_gemm<0>, dim3(MAX_WORK),   dim3(256), 0, stream,
                       x, W, bias, wsI, wsF, out);
  }
}

// Round 9
// 167.835 us; speedup vs baseline: 1.2071x; 1.2071x over previous
//
#include <hip/hip_runtime.h>
#include <hip/hip_bf16.h>

#define NB   16384
#define NE   64
#define DIN  128
#define DOUT 128
#define CPAD 32   // atomic counters on own 128B cache line

// ws layout in 4-byte words
#define WS_COUNTS   0         // 64*CPAD
#define WS_CURSOR   2048      // 64*CPAD
#define WS_BASE     4096      // 64
#define WS_NWORK    4160      // 1
#define WS_WORK     4224      // <= 832
#define WS_PICKED   8192      // 3*NB
#define WS_PW       57344     // 3*NB
#define WS_PAIRROW  106496    // 3*NB
#define WS_PAIRW    155648    // 3*NB
#define WS_PAIRP    204800    // 3*NB
#define WS_SLOT     253952    // 3*NB*128 floats -> ends at 6545408
#define WS_WH       6545408   // 64*128*128 bf16 = 524288 words (W hi, [e][o][d])
#define WS_WL       7069696   // 524288 words (W lo residual)
#define WS_END      7593984
#define MAX_WORK    832

typedef __attribute__((ext_vector_type(8))) short short8v;
typedef __attribute__((ext_vector_type(4))) float f32x4;

static __device__ __forceinline__ short f2bf(float f) {
  unsigned u = __float_as_uint(f);
  unsigned r = (u + 0x7fffu + ((u >> 16) & 1u)) >> 16;   // RNE
  return (short)r;
}
static __device__ __forceinline__ float bf2f(short s) {
  return __uint_as_float(((unsigned)(unsigned short)s) << 16);
}

__global__ __launch_bounds__(64) void k0_init(int* __restrict__ wsI) {
  if (threadIdx.x < NE) wsI[WS_COUNTS + threadIdx.x * CPAD] = 0;
}

__global__ __launch_bounds__(256) void k1_route(
    const float* __restrict__ x, const float* __restrict__ dsc,
    const float* __restrict__ cent, float* __restrict__ out,
    int* __restrict__ wsI, float* __restrict__ wsF, int zero_out) {
  __shared__ float cl[NE][132];
  __shared__ float xl[16][132];
  __shared__ float dl[4][64];
  const int tid = threadIdx.x;
  const int row0 = blockIdx.x * 16;

  const float4* c4 = (const float4*)cent;
  #pragma unroll
  for (int k = 0; k < 8; ++k) {
    int idx = tid + k * 256;
    int e = idx >> 5, dc = idx & 31;
    *(float4*)&cl[e][dc * 4] = c4[idx];
  }
  const float4* x4 = (const float4*)x + row0 * 32;
  #pragma unroll
  for (int k = 0; k < 2; ++k) {
    int idx = tid + k * 256;
    int r = idx >> 5, dc = idx & 31;
    *(float4*)&xl[r][dc * 4] = x4[idx];
  }
  if (zero_out) {
    float4* o4 = (float4*)out + row0 * 32;
    float4 z; z.x = z.y = z.z = z.w = 0.f;
    #pragma unroll
    for (int k = 0; k < 2; ++k) o4[tid + k * 256] = z;
  }
  __syncthreads();

  const int lane = tid & 63, wv = tid >> 6;
  const float ds = dsc[0];

  for (int rr = wv; rr < 16; rr += 4) {
    // distance_sq, numpy pairwise order (8 interleaved accs), contract off
    float4 r0 = {0.f, 0.f, 0.f, 0.f}, r1 = {0.f, 0.f, 0.f, 0.f};
    {
      #pragma clang fp contract(off)
      for (int i = 0; i < 16; ++i) {
        float4 xa = *(const float4*)&xl[rr][i * 8];
        float4 xb = *(const float4*)&xl[rr][i * 8 + 4];
        float4 ca = *(const float4*)&cl[lane][i * 8];
        float4 cb = *(const float4*)&cl[lane][i * 8 + 4];
        float t0 = ds * (xa.x - ca.x), t1 = ds * (xa.y - ca.y);
        float t2 = ds * (xa.z - ca.z), t3 = ds * (xa.w - ca.w);
        float u0 = ds * (xb.x - cb.x), u1 = ds * (xb.y - cb.y);
        float u2 = ds * (xb.z - cb.z), u3 = ds * (xb.w - cb.w);
        r0.x += t0 * t0; r0.y += t1 * t1; r0.z += t2 * t2; r0.w += t3 * t3;
        r1.x += u0 * u0; r1.y += u1 * u1; r1.z += u2 * u2; r1.w += u3 * u3;
      }
    }
    float s = ((r0.x + r0.y) + (r0.z + r0.w)) + ((r1.x + r1.y) + (r1.z + r1.w));
    float dist = s / 128.0f;

    // rank-based top-3; (dist, index) lex order == jax tie rule
    dl[wv][lane] = dist;
    int rank = 0;
    #pragma unroll
    for (int j = 0; j < 64; j += 8) {
      float4 da = *(const float4*)&dl[wv][j];
      float4 db = *(const float4*)&dl[wv][j + 4];
      rank += (da.x < dist || (da.x == dist && (j + 0) < lane)) ? 1 : 0;
      rank += (da.y < dist || (da.y == dist && (j + 1) < lane)) ? 1 : 0;
      rank += (da.z < dist || (da.z == dist && (j + 2) < lane)) ? 1 : 0;
      rank += (da.w < dist || (da.w == dist && (j + 3) < lane)) ? 1 : 0;
      rank += (db.x < dist || (db.x == dist && (j + 4) < lane)) ? 1 : 0;
      rank += (db.y < dist || (db.y == dist && (j + 5) < lane)) ? 1 : 0;
      rank += (db.z < dist || (db.z == dist && (j + 6) < lane)) ? 1 : 0;
      rank += (db.w < dist || (db.w == dist && (j + 7) < lane)) ? 1 : 0;
    }
    unsigned long long m0 = __ballot(rank == 0);
    unsigned long long m1 = __ballot(rank == 1);
    unsigned long long m2 = __ballot(rank == 2);
    int i0 = __ffsll(m0) - 1;
    int i1 = __ffsll(m1) - 1;
    int i2 = __ffsll(m2) - 1;

    float d0 = dl[wv][0], d1 = dl[wv][1], d2 = dl[wv][2];
    float w0 = 1.f / (1.f + d0), w1 = 1.f / (1.f + d1), w2 = 1.f / (1.f + d2);
    float sw = (w0 + w1) + w2;
    w0 /= sw; w1 /= sw; w2 /= sw;

    int row = row0 + rr;
    if (lane < 3) {
      float w = (lane == 0) ? w0 : ((lane == 1) ? w1 : w2);
      int p = (lane == 0) ? i0 : ((lane == 1) ? i1 : i2);
      wsI[WS_PICKED + row * 3 + lane] = p;
      wsF[WS_PW + row * 3 + lane] = w;
    }
  }
}

// block-LDS histogram -> few padded global atomics
__global__ __launch_bounds__(256) void k1b_count(int* __restrict__ wsI) {
  __shared__ int h[NE];
  const int tid = threadIdx.x;
  if (tid < NE) h[tid] = 0;
  __syncthreads();
  for (int i = blockIdx.x * 256 + tid; i < 3 * NB; i += 64 * 256)
    atomicAdd(&h[wsI[WS_PICKED + i]], 1);
  __syncthreads();
  if (tid < NE && h[tid]) atomicAdd(&wsI[WS_COUNTS + tid * CPAD], h[tid]);
}

__global__ __launch_bounds__(64) void k2_scan(int* __restrict__ wsI) {
  const int lane = threadIdx.x;
  int cnt = wsI[WS_COUNTS + lane * CPAD];
  int xs = cnt;
  #pragma unroll
  for (int off = 1; off < 64; off <<= 1) {
    int y = __shfl_up(xs, off, 64);
    if (lane >= off) xs += y;
  }
  int excl = xs - cnt;
  wsI[WS_BASE + lane] = excl;
  wsI[WS_CURSOR + lane * CPAD] = excl;
  int nt = (cnt + 63) >> 6;
  int ts = nt;
  #pragma unroll
  for (int off = 1; off < 64; off <<= 1) {
    int y = __shfl_up(ts, off, 64);
    if (lane >= off) ts += y;
  }
  int texcl = ts - nt;
  for (int t = 0; t < nt; ++t) wsI[WS_WORK + texcl + t] = (lane << 16) | t;
  if (lane == 63) wsI[WS_NWORK] = ts;
}

__global__ __launch_bounds__(256) void k3_scatter(int* __restrict__ wsI,
                                                  float* __restrict__ wsF) {
  int p = blockIdx.x * 256 + threadIdx.x;
  if (p < 3 * NB) {
    int e = wsI[WS_PICKED + p];
    float w = wsF[WS_PW + p];
    int pos = atomicAdd(&wsI[WS_CURSOR + e * CPAD], 1);
    wsI[WS_PAIRROW + pos] = p / 3;
    wsI[WS_PAIRP + pos]   = p;
    wsF[WS_PAIRW + pos]   = w;
  }
}

// One-time W split: gwh/gwl[e][o][d] bf16 hi/residual, transposed.
// Block = (expert, K-half). Coalesced f4 reads, LDS transpose, short8 writes.
__global__ __launch_bounds__(256) void k_wsplit(const float* __restrict__ W,
                                                short* __restrict__ gwh,
                                                short* __restrict__ gwl) {
  __shared__ float T[DOUT][68];   // [o][d_loc 0..63], pad 68
  const int e = blockIdx.x >> 1, kh = blockIdx.x & 1;
  const int tid = threadIdx.x;
  const float4* Wg = (const float4*)(W + (long)e * DIN * DOUT);

  #pragma unroll
  for (int k = 0; k < 8; ++k) {
    int idx = tid + k * 256;          // 0..2047
    int dl = idx >> 5, o4 = idx & 31;
    float4 v = Wg[(long)(64 * kh + dl) * 32 + o4];
    T[4 * o4 + 0][dl] = v.x;
    T[4 * o4 + 1][dl] = v.y;
    T[4 * o4 + 2][dl] = v.z;
    T[4 * o4 + 3][dl] = v.w;
  }
  __syncthreads();

  #pragma unroll
  for (int it = 0; it < 4; ++it) {
    int task = tid + it * 256;        // 0..1023
    int o = task >> 3, dc = task & 7;
    const float* tp = &T[o][8 * dc];
    short8v wh, wl;
    #pragma unroll
    for (int i = 0; i < 8; ++i) {
      float f = tp[i];
      short h = f2bf(f);
      wh[i] = h;
      wl[i] = f2bf(f - bf2f(h));
    }
    long base = ((long)e * DOUT + o) * DIN + 64 * kh + 8 * dc;
    *(short8v*)&gwh[base] = wh;
    *(short8v*)&gwl[base] = wl;
  }
}

// MFMA k4: B fragments straight from pre-split global (L2-resident); no W LDS.
__global__ __launch_bounds__(256) void k4_mfma(
    const float* __restrict__ x, const short* __restrict__ gwh,
    const short* __restrict__ gwl, const float* __restrict__ bias,
    const int* __restrict__ wsI, const float* __restrict__ wsF,
    float* __restrict__ dst) {
  __shared__ float biasl[DOUT];
  __shared__ int   rowsl[64];
  __shared__ int   pl[64];
  __shared__ float wgt[64];

  const int nwork = wsI[WS_NWORK];
  const int bid = blockIdx.x;
  if (bid >= nwork) return;
  const int wk = wsI[WS_WORK + bid];
  const int e = wk >> 16, t = wk & 0xffff;
  const int cnt = wsI[WS_COUNTS + e * CPAD];
  const int srcb = wsI[WS_BASE + e] + t * 64;
  const int m = min(64, cnt - t * 64);
  const int tid = threadIdx.x;
  const int lane = tid & 63, wv = tid >> 6;
  const int l15 = lane & 15, kg = lane >> 4;

  if (tid < 64) {
    int src = srcb + ((tid < m) ? tid : 0);
    rowsl[tid] = wsI[WS_PAIRROW + src];
    pl[tid]    = wsI[WS_PAIRP + src];
    wgt[tid]   = (tid < m) ? wsF[WS_PAIRW + srcb + tid] : 0.f;
  }
  if (tid < DOUT) biasl[tid] = bias[e * DOUT + tid];
  __syncthreads();

  // A fragments: row rowsl[16*wv+l15], k = 32s + 8kg + i; fp32 -> bf16 hi/lo
  const float* xr = x + (long)rowsl[16 * wv + l15] * DIN + 8 * kg;
  short8v ah[4], al[4];
  #pragma unroll
  for (int s = 0; s < 4; ++s) {
    float4 fa = *(const float4*)(xr + 32 * s);
    float4 fb = *(const float4*)(xr + 32 * s + 4);
    float f[8] = {fa.x, fa.y, fa.z, fa.w, fb.x, fb.y, fb.z, fb.w};
    #pragma unroll
    for (int i = 0; i < 8; ++i) {
      short h = f2bf(f[i]);
      ah[s][i] = h;
      al[s][i] = f2bf(f[i] - bf2f(h));
    }
  }

  f32x4 acc[8];
  #pragma unroll
  for (int n = 0; n < 8; ++n) acc[n] = (f32x4){0.f, 0.f, 0.f, 0.f};

  const long ebase = (long)e * DOUT * DIN;
  #pragma unroll
  for (int n = 0; n < 8; ++n) {
    const long obase = ebase + (long)(16 * n + l15) * DIN + 8 * kg;
    #pragma unroll
    for (int s = 0; s < 4; ++s) {
      short8v bh = *(const short8v*)&gwh[obase + 32 * s];
      short8v bl = *(const short8v*)&gwl[obase + 32 * s];
      acc[n] = __builtin_amdgcn_mfma_f32_16x16x32_bf16(ah[s], bh, acc[n], 0, 0, 0);
      acc[n] = __builtin_amdgcn_mfma_f32_16x16x32_bf16(ah[s], bl, acc[n], 0, 0, 0);
      acc[n] = __builtin_amdgcn_mfma_f32_16x16x32_bf16(al[s], bh, acc[n], 0, 0, 0);
    }
  }

  // C/D: col = l15 (within n-tile), local row = 16*wv + 4*kg + j
  #pragma unroll
  for (int j = 0; j < 4; ++j) {
    int r = 16 * wv + 4 * kg + j;
    if (r < m) {
      float w = wgt[r];
      #pragma unroll
      for (int n = 0; n < 8; ++n) {
        int o = 16 * n + l15;
        dst[(long)pl[r] * DOUT + o] = w * (acc[n][j] + biasl[o]);
      }
    }
  }
}

// fp32 atomic fallback (small-ws path only)
__global__ __launch_bounds__(256) void k4_f32(
    const float* __restrict__ x, const float* __restrict__ W,
    const float* __restrict__ bias, const int* __restrict__ wsI,
    const float* __restrict__ wsF, float* __restrict__ dst) {
  __shared__ float xT[DIN][68];
  __shared__ float Wl[32][DOUT];
  __shared__ int   rowsl[64];
  __shared__ float wl[64];

  const int nwork = wsI[WS_NWORK];
  const int bid = blockIdx.x;
  if (bid >= nwork) return;
  const int wk = wsI[WS_WORK + bid];
  const int e = wk >> 16, t = wk & 0xffff;
  const int cnt = wsI[WS_COUNTS + e * CPAD];
  const int srcb = wsI[WS_BASE + e] + t * 64;
  const int m = min(64, cnt - t * 64);
  const int tid = threadIdx.x;

  if (tid < 64) {
    int src = srcb + ((tid < m) ? tid : 0);
    rowsl[tid] = wsI[WS_PAIRROW + src];
    wl[tid] = (tid < m) ? wsF[WS_PAIRW + srcb + tid] : 0.f;
  }
  __syncthreads();
  {
    int r = tid >> 2;
    int d0 = (tid & 3) * 32;
    const float* xr = x + (long)rowsl[r] * DIN + d0;
    #pragma unroll
    for (int k = 0; k < 32; k += 4) {
      float4 v = *(const float4*)(xr + k);
      xT[d0 + k + 0][r] = v.x;
      xT[d0 + k + 1][r] = v.y;
      xT[d0 + k + 2][r] = v.z;
      xT[d0 + k + 3][r] = v.w;
    }
  }
  float acc[4][8];
  #pragma unroll
  for (int i = 0; i < 4; ++i)
    #pragma unroll
    for (int j = 0; j < 8; ++j) acc[i][j] = 0.f;
  const int tr = tid & 15, tc = tid >> 4;
  for (int dc = 0; dc < DIN; dc += 32) {
    __syncthreads();
    const float4* Wg = (const float4*)(W + (long)e * DIN * DOUT + dc * DOUT);
    float4* Wl4 = (float4*)&Wl[0][0];
    #pragma unroll
    for (int k = 0; k < 4; ++k) Wl4[tid + k * 256] = Wg[tid + k * 256];
    __syncthreads();
    #pragma unroll 8
    for (int dd = 0; dd < 32; ++dd) {
      float4 xv = *(const float4*)&xT[dc + dd][tr * 4];
      float4 wa = *(const float4*)&Wl[dd][tc * 8];
      float4 wb = *(const float4*)&Wl[dd][tc * 8 + 4];
      float xs[4] = {xv.x, xv.y, xv.z, xv.w};
      float ws8[8] = {wa.x, wa.y, wa.z, wa.w, wb.x, wb.y, wb.z, wb.w};
      #pragma unroll
      for (int i = 0; i < 4; ++i)
        #pragma unroll
        for (int j = 0; j < 8; ++j) acc[i][j] += xs[i] * ws8[j];
    }
  }
  #pragma unroll
  for (int i = 0; i < 4; ++i) {
    int r = tr * 4 + i;
    if (r < m) {
      int row = rowsl[r];
      float w = wl[r];
      float* op = dst + (long)row * DOUT + tc * 8;
      const float* bp = bias + (long)e * DOUT + tc * 8;
      #pragma unroll
      for (int j = 0; j < 8; ++j) atomicAdd(&op[j], w * (acc[i][j] + bp[j]));
    }
  }
}

__global__ __launch_bounds__(256) void k5_gather(const float* __restrict__ slot,
                                                 float* __restrict__ out) {
  int gid = blockIdx.x * 256 + threadIdx.x;
  int row = gid >> 5, c4 = gid & 31;
  const float4* s = (const float4*)(slot + (long)row * 3 * DOUT) + c4;
  float4 a = s[0], b = s[32], c = s[64];
  float4 o;
  o.x = (a.x + b.x) + c.x;
  o.y = (a.y + b.y) + c.y;
  o.z = (a.z + b.z) + c.z;
  o.w = (a.w + b.w) + c.w;
  ((float4*)out)[gid] = o;
}

extern "C" void kernel_launch(void* const* d_in, const int* in_sizes, int n_in,
                              void* d_out, int out_size, void* d_ws, size_t ws_size,
                              hipStream_t stream) {
  const float* x    = (const float*)d_in[0];
  const float* dsc  = (const float*)d_in[1];
  const float* cent = (const float*)d_in[2];
  const float* W    = (const float*)d_in[3];
  const float* bias = (const float*)d_in[4];
  float* out = (float*)d_out;
  int* wsI = (int*)d_ws;
  float* wsF = (float*)d_ws;

  const size_t need = (size_t)WS_END * 4;
  const int useSlot = (ws_size >= need) ? 1 : 0;

  hipLaunchKernelGGL(k0_init,    dim3(1),            dim3(64),  0, stream, wsI);
  hipLaunchKernelGGL(k1_route,   dim3(NB / 16),      dim3(256), 0, stream,
                     x, dsc, cent, out, wsI, wsF, useSlot ? 0 : 1);
  hipLaunchKernelGGL(k1b_count,  dim3(64),           dim3(256), 0, stream, wsI);
  hipLaunchKernelGGL(k2_scan,    dim3(1),            dim3(64),  0, stream, wsI);
  hipLaunchKernelGGL(k3_scatter, dim3(3 * NB / 256), dim3(256), 0, stream, wsI, wsF);
  if (useSlot) {
    float* slot = (float*)d_ws + WS_SLOT;
    short* gwh  = (short*)(wsI + WS_WH);
    short* gwl  = (short*)(wsI + WS_WL);
    hipLaunchKernelGGL(k_wsplit,  dim3(2 * NE),      dim3(256), 0, stream, W, gwh, gwl);
    hipLaunchKernelGGL(k4_mfma,   dim3(MAX_WORK),    dim3(256), 0, stream,
                       x, gwh, gwl, bias, wsI, wsF, slot);
    hipLaunchKernelGGL(k5_gather, dim3(NB * 32 / 256), dim3(256), 0, stream, slot, out);
  } else {
    hipLaunchKernelGGL(k4_f32,    dim3(MAX_WORK),    dim3(256), 0, stream,
                       x, W, bias, wsI, wsF, out);
  }
}

// Round 10
// 158.192 us; speedup vs baseline: 1.2807x; 1.0610x over previous
//
#include <hip/hip_runtime.h>
#include <hip/hip_bf16.h>

#define NB   16384
#define NE   64
#define DIN  128
#define DOUT 128
#define CPAD 32   // atomic counters on own 128B cache line

// ws layout in 4-byte words
#define WS_COUNTS   0         // 64*CPAD
#define WS_CURSOR   2048      // 64*CPAD
#define WS_BASE     4096      // 64
#define WS_NWORK    4160      // 1
#define WS_WORK     4224      // <= 832
#define WS_HIST     5120      // 64 blocks x 64 experts
#define WS_PICKED   9216      // 3*NB
#define WS_PW       58368     // 3*NB
#define WS_PAIRROW  107520    // 3*NB
#define WS_PAIRW    156672    // 3*NB
#define WS_PAIRP    205824    // 3*NB
#define WS_SLOT     254976    // 3*NB*128 floats
#define WS_WH       6546432   // 64*128*128 bf16 (W hi, [e][o][d])
#define WS_WL       7070720   // residual
#define WS_END      7595008
#define MAX_WORK    832

typedef __attribute__((ext_vector_type(8))) short short8v;
typedef __attribute__((ext_vector_type(4))) float f32x4;

static __device__ __forceinline__ short f2bf(float f) {
  unsigned u = __float_as_uint(f);
  unsigned r = (u + 0x7fffu + ((u >> 16) & 1u)) >> 16;   // RNE
  return (short)r;
}
static __device__ __forceinline__ float bf2f(short s) {
  return __uint_as_float(((unsigned)(unsigned short)s) << 16);
}

// k1: centroids-only LDS; x via wave-uniform global broadcast loads;
// 4 rows per k-iteration (centroid b128 reads amortized 4x; 32 FMA chains).
// Per-element arithmetic bit-identical to the validated kernel.
__global__ __launch_bounds__(256) void k1_route(
    const float* __restrict__ x, const float* __restrict__ dsc,
    const float* __restrict__ cent,
    int* __restrict__ wsI, float* __restrict__ wsF) {
  __shared__ float cl[NE][132];
  __shared__ float dl[4][64];
  const int tid = threadIdx.x;
  const int row0 = blockIdx.x * 16;

  const float4* c4 = (const float4*)cent;
  #pragma unroll
  for (int k = 0; k < 8; ++k) {
    int idx = tid + k * 256;
    int e = idx >> 5, dc = idx & 31;
    *(float4*)&cl[e][dc * 4] = c4[idx];
  }
  __syncthreads();

  const int lane = tid & 63, wv = tid >> 6;
  const float ds = dsc[0];
  const int rbase = row0 + 4 * wv;
  const float* xr = x + (long)rbase * DIN;

  float4 r0[4], r1[4];
  #pragma unroll
  for (int r = 0; r < 4; ++r) {
    r0[r] = (float4){0.f, 0.f, 0.f, 0.f};
    r1[r] = (float4){0.f, 0.f, 0.f, 0.f};
  }
  {
    #pragma clang fp contract(off)
    for (int i = 0; i < 16; ++i) {
      float4 ca = *(const float4*)&cl[lane][i * 8];
      float4 cb = *(const float4*)&cl[lane][i * 8 + 4];
      #pragma unroll
      for (int r = 0; r < 4; ++r) {
        float4 xa = *(const float4*)(xr + r * DIN + i * 8);      // broadcast
        float4 xb = *(const float4*)(xr + r * DIN + i * 8 + 4);  // broadcast
        float t0 = ds * (xa.x - ca.x), t1 = ds * (xa.y - ca.y);
        float t2 = ds * (xa.z - ca.z), t3 = ds * (xa.w - ca.w);
        float u0 = ds * (xb.x - cb.x), u1 = ds * (xb.y - cb.y);
        float u2 = ds * (xb.z - cb.z), u3 = ds * (xb.w - cb.w);
        r0[r].x += t0 * t0; r0[r].y += t1 * t1;
        r0[r].z += t2 * t2; r0[r].w += t3 * t3;
        r1[r].x += u0 * u0; r1[r].y += u1 * u1;
        r1[r].z += u2 * u2; r1[r].w += u3 * u3;
      }
    }
  }
  float distr[4];
  #pragma unroll
  for (int r = 0; r < 4; ++r) {
    float s = ((r0[r].x + r0[r].y) + (r0[r].z + r0[r].w)) +
              ((r1[r].x + r1[r].y) + (r1[r].z + r1[r].w));
    distr[r] = s / 128.0f;
  }

  #pragma unroll
  for (int r = 0; r < 4; ++r) {
    float dist = distr[r];
    // rank-based top-3; (dist, index) lex order == jax tie rule
    dl[wv][lane] = dist;
    int rank = 0;
    #pragma unroll
    for (int j = 0; j < 64; j += 8) {
      float4 da = *(const float4*)&dl[wv][j];
      float4 db = *(const float4*)&dl[wv][j + 4];
      rank += (da.x < dist || (da.x == dist && (j + 0) < lane)) ? 1 : 0;
      rank += (da.y < dist || (da.y == dist && (j + 1) < lane)) ? 1 : 0;
      rank += (da.z < dist || (da.z == dist && (j + 2) < lane)) ? 1 : 0;
      rank += (da.w < dist || (da.w == dist && (j + 3) < lane)) ? 1 : 0;
      rank += (db.x < dist || (db.x == dist && (j + 4) < lane)) ? 1 : 0;
      rank += (db.y < dist || (db.y == dist && (j + 5) < lane)) ? 1 : 0;
      rank += (db.z < dist || (db.z == dist && (j + 6) < lane)) ? 1 : 0;
      rank += (db.w < dist || (db.w == dist && (j + 7) < lane)) ? 1 : 0;
    }
    unsigned long long m0 = __ballot(rank == 0);
    unsigned long long m1 = __ballot(rank == 1);
    unsigned long long m2 = __ballot(rank == 2);
    int i0 = __ffsll(m0) - 1;
    int i1 = __ffsll(m1) - 1;
    int i2 = __ffsll(m2) - 1;

    // weights from experts 0,1,2 distances (reference quirk: [:, :es])
    float d0 = dl[wv][0], d1 = dl[wv][1], d2 = dl[wv][2];
    float w0 = 1.f / (1.f + d0), w1 = 1.f / (1.f + d1), w2 = 1.f / (1.f + d2);
    float sw = (w0 + w1) + w2;
    w0 /= sw; w1 /= sw; w2 /= sw;

    int row = rbase + r;
    if (lane < 3) {
      float w = (lane == 0) ? w0 : ((lane == 1) ? w1 : w2);
      int p = (lane == 0) ? i0 : ((lane == 1) ? i1 : i2);
      wsI[WS_PICKED + row * 3 + lane] = p;
      wsF[WS_PW + row * 3 + lane] = w;
    }
  }
}

// private per-block histograms (no atomics, no init kernel needed)
__global__ __launch_bounds__(256) void k1b_count(int* __restrict__ wsI) {
  __shared__ int h[NE];
  const int tid = threadIdx.x;
  if (tid < NE) h[tid] = 0;
  __syncthreads();
  const int base = blockIdx.x * 768;
  #pragma unroll
  for (int k = 0; k < 3; ++k)
    atomicAdd(&h[wsI[WS_PICKED + base + tid + k * 256]], 1);
  __syncthreads();
  if (tid < NE) wsI[WS_HIST + blockIdx.x * NE + tid] = h[tid];
}

// sum hists -> counts, prefix scan -> bases/cursors, worklist
__global__ __launch_bounds__(64) void k2_scan(int* __restrict__ wsI) {
  const int lane = threadIdx.x;
  int cnt = 0;
  for (int b = 0; b < 64; ++b) cnt += wsI[WS_HIST + b * NE + lane];
  wsI[WS_COUNTS + lane * CPAD] = cnt;
  int xs = cnt;
  #pragma unroll
  for (int off = 1; off < 64; off <<= 1) {
    int y = __shfl_up(xs, off, 64);
    if (lane >= off) xs += y;
  }
  int excl = xs - cnt;
  wsI[WS_BASE + lane] = excl;
  wsI[WS_CURSOR + lane * CPAD] = excl;
  int nt = (cnt + 63) >> 6;
  int ts = nt;
  #pragma unroll
  for (int off = 1; off < 64; off <<= 1) {
    int y = __shfl_up(ts, off, 64);
    if (lane >= off) ts += y;
  }
  int texcl = ts - nt;
  for (int t = 0; t < nt; ++t) wsI[WS_WORK + texcl + t] = (lane << 16) | t;
  if (lane == 63) wsI[WS_NWORK] = ts;
}

// two-level scatter: LDS-rank within block + one padded global atomic per
// (block, expert). Order within an expert is irrelevant downstream.
__global__ __launch_bounds__(256) void k3_scatter(int* __restrict__ wsI,
                                                  float* __restrict__ wsF) {
  __shared__ int h[NE];
  __shared__ int hbase[NE];
  const int tid = threadIdx.x;
  if (tid < NE) h[tid] = 0;
  __syncthreads();
  int p = blockIdx.x * 256 + tid;
  int e = wsI[WS_PICKED + p];
  float w = wsF[WS_PW + p];
  int myofs = atomicAdd(&h[e], 1);
  __syncthreads();
  if (tid < NE && h[tid])
    hbase[tid] = atomicAdd(&wsI[WS_CURSOR + tid * CPAD], h[tid]);
  __syncthreads();
  int pos = hbase[e] + myofs;
  wsI[WS_PAIRROW + pos] = p / 3;
  wsI[WS_PAIRP + pos]   = p;
  wsF[WS_PAIRW + pos]   = w;
}

// One-time W split: gwh/gwl[e][o][d] bf16 hi/residual, transposed.
__global__ __launch_bounds__(256) void k_wsplit(const float* __restrict__ W,
                                                short* __restrict__ gwh,
                                                short* __restrict__ gwl) {
  __shared__ float T[DOUT][68];
  const int e = blockIdx.x >> 1, kh = blockIdx.x & 1;
  const int tid = threadIdx.x;
  const float4* Wg = (const float4*)(W + (long)e * DIN * DOUT);

  #pragma unroll
  for (int k = 0; k < 8; ++k) {
    int idx = tid + k * 256;
    int dl = idx >> 5, o4 = idx & 31;
    float4 v = Wg[(long)(64 * kh + dl) * 32 + o4];
    T[4 * o4 + 0][dl] = v.x;
    T[4 * o4 + 1][dl] = v.y;
    T[4 * o4 + 2][dl] = v.z;
    T[4 * o4 + 3][dl] = v.w;
  }
  __syncthreads();

  #pragma unroll
  for (int it = 0; it < 4; ++it) {
    int task = tid + it * 256;
    int o = task >> 3, dc = task & 7;
    const float* tp = &T[o][8 * dc];
    short8v wh, wl;
    #pragma unroll
    for (int i = 0; i < 8; ++i) {
      float f = tp[i];
      short h = f2bf(f);
      wh[i] = h;
      wl[i] = f2bf(f - bf2f(h));
    }
    long base = ((long)e * DOUT + o) * DIN + 64 * kh + 8 * dc;
    *(short8v*)&gwh[base] = wh;
    *(short8v*)&gwl[base] = wl;
  }
}

// MFMA k4: B fragments straight from pre-split global (L2/L3-resident).
__global__ __launch_bounds__(256) void k4_mfma(
    const float* __restrict__ x, const short* __restrict__ gwh,
    const short* __restrict__ gwl, const float* __restrict__ bias,
    const int* __restrict__ wsI, const float* __restrict__ wsF,
    float* __restrict__ dst) {
  __shared__ float biasl[DOUT];
  __shared__ int   rowsl[64];
  __shared__ int   pl[64];
  __shared__ float wgt[64];

  const int nwork = wsI[WS_NWORK];
  const int bid = blockIdx.x;
  if (bid >= nwork) return;
  const int wk = wsI[WS_WORK + bid];
  const int e = wk >> 16, t = wk & 0xffff;
  const int cnt = wsI[WS_COUNTS + e * CPAD];
  const int srcb = wsI[WS_BASE + e] + t * 64;
  const int m = min(64, cnt - t * 64);
  const int tid = threadIdx.x;
  const int lane = tid & 63, wv = tid >> 6;
  const int l15 = lane & 15, kg = lane >> 4;

  if (tid < 64) {
    int src = srcb + ((tid < m) ? tid : 0);
    rowsl[tid] = wsI[WS_PAIRROW + src];
    pl[tid]    = wsI[WS_PAIRP + src];
    wgt[tid]   = (tid < m) ? wsF[WS_PAIRW + srcb + tid] : 0.f;
  }
  if (tid < DOUT) biasl[tid] = bias[e * DOUT + tid];
  __syncthreads();

  const float* xr = x + (long)rowsl[16 * wv + l15] * DIN + 8 * kg;
  short8v ah[4], al[4];
  #pragma unroll
  for (int s = 0; s < 4; ++s) {
    float4 fa = *(const float4*)(xr + 32 * s);
    float4 fb = *(const float4*)(xr + 32 * s + 4);
    float f[8] = {fa.x, fa.y, fa.z, fa.w, fb.x, fb.y, fb.z, fb.w};
    #pragma unroll
    for (int i = 0; i < 8; ++i) {
      short h = f2bf(f[i]);
      ah[s][i] = h;
      al[s][i] = f2bf(f[i] - bf2f(h));
    }
  }

  f32x4 acc[8];
  #pragma unroll
  for (int n = 0; n < 8; ++n) acc[n] = (f32x4){0.f, 0.f, 0.f, 0.f};

  const long ebase = (long)e * DOUT * DIN;
  #pragma unroll
  for (int n = 0; n < 8; ++n) {
    const long obase = ebase + (long)(16 * n + l15) * DIN + 8 * kg;
    #pragma unroll
    for (int s = 0; s < 4; ++s) {
      short8v bh = *(const short8v*)&gwh[obase + 32 * s];
      short8v bl = *(const short8v*)&gwl[obase + 32 * s];
      acc[n] = __builtin_amdgcn_mfma_f32_16x16x32_bf16(ah[s], bh, acc[n], 0, 0, 0);
      acc[n] = __builtin_amdgcn_mfma_f32_16x16x32_bf16(ah[s], bl, acc[n], 0, 0, 0);
      acc[n] = __builtin_amdgcn_mfma_f32_16x16x32_bf16(al[s], bh, acc[n], 0, 0, 0);
    }
  }

  #pragma unroll
  for (int j = 0; j < 4; ++j) {
    int r = 16 * wv + 4 * kg + j;
    if (r < m) {
      float w = wgt[r];
      #pragma unroll
      for (int n = 0; n < 8; ++n) {
        int o = 16 * n + l15;
        dst[(long)pl[r] * DOUT + o] = w * (acc[n][j] + biasl[o]);
      }
    }
  }
}

__global__ __launch_bounds__(256) void k5_gather(const float* __restrict__ slot,
                                                 float* __restrict__ out) {
  int gid = blockIdx.x * 256 + threadIdx.x;
  int row = gid >> 5, c4 = gid & 31;
  const float4* s = (const float4*)(slot + (long)row * 3 * DOUT) + c4;
  float4 a = s[0], b = s[32], c = s[64];
  float4 o;
  o.x = (a.x + b.x) + c.x;
  o.y = (a.y + b.y) + c.y;
  o.z = (a.z + b.z) + c.z;
  o.w = (a.w + b.w) + c.w;
  ((float4*)out)[gid] = o;
}

// fp32 atomic fallback (small-ws path only)
__global__ __launch_bounds__(256) void k4_f32(
    const float* __restrict__ x, const float* __restrict__ W,
    const float* __restrict__ bias, const int* __restrict__ wsI,
    const float* __restrict__ wsF, float* __restrict__ dst) {
  __shared__ float xT[DIN][68];
  __shared__ float Wl[32][DOUT];
  __shared__ int   rowsl[64];
  __shared__ float wl[64];
  const int nwork = wsI[WS_NWORK];
  const int bid = blockIdx.x;
  if (bid >= nwork) return;
  const int wk = wsI[WS_WORK + bid];
  const int e = wk >> 16, t = wk & 0xffff;
  const int cnt = wsI[WS_COUNTS + e * CPAD];
  const int srcb = wsI[WS_BASE + e] + t * 64;
  const int m = min(64, cnt - t * 64);
  const int tid = threadIdx.x;
  if (tid < 64) {
    int src = srcb + ((tid < m) ? tid : 0);
    rowsl[tid] = wsI[WS_PAIRROW + src];
    wl[tid] = (tid < m) ? wsF[WS_PAIRW + srcb + tid] : 0.f;
  }
  __syncthreads();
  {
    int r = tid >> 2;
    int d0 = (tid & 3) * 32;
    const float* xrw = x + (long)rowsl[r] * DIN + d0;
    #pragma unroll
    for (int k = 0; k < 32; k += 4) {
      float4 v = *(const float4*)(xrw + k);
      xT[d0 + k + 0][r] = v.x;
      xT[d0 + k + 1][r] = v.y;
      xT[d0 + k + 2][r] = v.z;
      xT[d0 + k + 3][r] = v.w;
    }
  }
  float acc[4][8];
  #pragma unroll
  for (int i = 0; i < 4; ++i)
    #pragma unroll
    for (int j = 0; j < 8; ++j) acc[i][j] = 0.f;
  const int tr = tid & 15, tc = tid >> 4;
  for (int dc = 0; dc < DIN; dc += 32) {
    __syncthreads();
    const float4* Wg = (const float4*)(W + (long)e * DIN * DOUT + dc * DOUT);
    float4* Wl4 = (float4*)&Wl[0][0];
    #pragma unroll
    for (int k = 0; k < 4; ++k) Wl4[tid + k * 256] = Wg[tid + k * 256];
    __syncthreads();
    #pragma unroll 8
    for (int dd = 0; dd < 32; ++dd) {
      float4 xv = *(const float4*)&xT[dc + dd][tr * 4];
      float4 wa = *(const float4*)&Wl[dd][tc * 8];
      float4 wb = *(const float4*)&Wl[dd][tc * 8 + 4];
      float xs[4] = {xv.x, xv.y, xv.z, xv.w};
      float ws8[8] = {wa.x, wa.y, wa.z, wa.w, wb.x, wb.y, wb.z, wb.w};
      #pragma unroll
      for (int i = 0; i < 4; ++i)
        #pragma unroll
        for (int j = 0; j < 8; ++j) acc[i][j] += xs[i] * ws8[j];
    }
  }
  #pragma unroll
  for (int i = 0; i < 4; ++i) {
    int r = tr * 4 + i;
    if (r < m) {
      int row = rowsl[r];
      float w = wl[r];
      float* op = dst + (long)row * DOUT + tc * 8;
      const float* bp = bias + (long)e * DOUT + tc * 8;
      #pragma unroll
      for (int j = 0; j < 8; ++j) atomicAdd(&op[j], w * (acc[i][j] + bp[j]));
    }
  }
}

__global__ __launch_bounds__(256) void k_zero_out(float* __restrict__ out) {
  float4 z; z.x = z.y = z.z = z.w = 0.f;
  ((float4*)out)[blockIdx.x * 256 + threadIdx.x] = z;
}

extern "C" void kernel_launch(void* const* d_in, const int* in_sizes, int n_in,
                              void* d_out, int out_size, void* d_ws, size_t ws_size,
                              hipStream_t stream) {
  const float* x    = (const float*)d_in[0];
  const float* dsc  = (const float*)d_in[1];
  const float* cent = (const float*)d_in[2];
  const float* W    = (const float*)d_in[3];
  const float* bias = (const float*)d_in[4];
  float* out = (float*)d_out;
  int* wsI = (int*)d_ws;
  float* wsF = (float*)d_ws;

  const size_t need = (size_t)WS_END * 4;
  const int useSlot = (ws_size >= need) ? 1 : 0;

  hipLaunchKernelGGL(k1_route,   dim3(NB / 16),      dim3(256), 0, stream,
                     x, dsc, cent, wsI, wsF);
  hipLaunchKernelGGL(k1b_count,  dim3(64),           dim3(256), 0, stream, wsI);
  hipLaunchKernelGGL(k2_scan,    dim3(1),            dim3(64),  0, stream, wsI);
  hipLaunchKernelGGL(k3_scatter, dim3(3 * NB / 256), dim3(256), 0, stream, wsI, wsF);
  if (useSlot) {
    float* slot = (float*)d_ws + WS_SLOT;
    short* gwh  = (short*)(wsI + WS_WH);
    short* gwl  = (short*)(wsI + WS_WL);
    hipLaunchKernelGGL(k_wsplit,  dim3(2 * NE),      dim3(256), 0, stream, W, gwh, gwl);
    hipLaunchKernelGGL(k4_mfma,   dim3(MAX_WORK),    dim3(256), 0, stream,
                       x, gwh, gwl, bias, wsI, wsF, slot);
    hipLaunchKernelGGL(k5_gather, dim3(NB * 32 / 256), dim3(256), 0, stream, slot, out);
  } else {
    hipLaunchKernelGGL(k_zero_out, dim3(NB * 32 / 256), dim3(256), 0, stream, out);
    hipLaunchKernelGGL(k4_f32,    dim3(MAX_WORK),    dim3(256), 0, stream,
                       x, W, bias, wsI, wsF, out);
  }
}